// Round 5
// baseline (880.118 us; speedup 1.0000x reference)
//
#include <hip/hip_runtime.h>
#include <math.h>

// PhyloNeighbours: per-filter (16) kNN (k=8) over 2000 features, 512-dim coords.
// v10 = v9 with approx at 3 blocks/CU (LDS 74.75KB -> 49KB).
// v9 post-mortem: approx 433us with NOTHING saturated (Mfma 6.5%, VALU 25%,
// HBM 7%); the only lever that has moved it is residency (1->2 blocks/CU:
// 629->433). v10: (a) staging 3-buffer rotation -> 2-buffer ping-pong
// (depth-1 prefetch, vmcnt(6)); (b) Dl [128][128] -> [128][64], epilogue/scan
// in 4 phases of 64 j (top-10 lex-insert is arrival-order-independent ->
// identical candidate sets -> bit-identical output); (c) launch_bounds
// (256,3). MFMA/staging arithmetic, swizzles, insert/merge logic unchanged.
// refine: v9 wave-cooperative (validated). Other kernels unchanged.
//
// Memory plan:
//   d_out: phase 1 holds cbt[f][2048][512] bf16 (32 MB); phase 2 holds
//          ct[f][2000][512] fp32 (exactly out_size floats); final gather output.
//   d_ws : sq 128KB + cand 2.56MB + dval 2.56MB + fidx 1MB ~= 6.3 MB.

#define F_TOT 2000
#define CF    16
#define KDIM  512
#define NB_K  8
#define IPAD  2048
#define NCAND 10
#define NCH   2
#define NCTOT (NCAND * NCH)

typedef __attribute__((ext_vector_type(8))) short bf16x8;
typedef __attribute__((ext_vector_type(4))) float f32x4;

__device__ inline unsigned short f2bf(float x) {
  unsigned int u = __float_as_uint(x);
  return (unsigned short)((u + 0x7fffu + ((u >> 16) & 1u)) >> 16);
}

// async 16B global -> LDS (LDS dest: wave-uniform base + lane*16)
#define GLOAD_LDS16(gp, lp)                                                          \
  __builtin_amdgcn_global_load_lds((const __attribute__((address_space(1))) void*)(gp), \
                                   (__attribute__((address_space(3))) void*)(lp), 16, 0, 0)

// ---------------------------------------------------------------- k1: sq (fp64)
// VALIDATED rounds 1-4 — do not change arithmetic.
__global__ __launch_bounds__(256) void sq_kernel(const float* __restrict__ coords,
                                                 float* __restrict__ sq_out) {
  int i = blockIdx.x;
  int t = threadIdx.x;
  int f = t & 15;
  int cg = t >> 4;
  const float* base = coords + (size_t)i * CF + f;
  double s = 0.0;
  for (int c = cg * 32; c < cg * 32 + 32; ++c) {
    float v = base[(size_t)c * (F_TOT * CF)];
    s += (double)v * (double)v;
  }
  __shared__ double red[256];
  red[t] = s;
  __syncthreads();
  if (cg == 0) {
    double tot = 0.0;
#pragma unroll
    for (int g = 0; g < 16; ++g) tot += red[g * 16 + f];
    sq_out[i * CF + f] = (float)tot;
  }
}

// ------------------------------------------- k2: coords -> cbt[f][i pad2048][c] bf16
__global__ __launch_bounds__(256) void cvt_bf16_kernel(const float* __restrict__ coords,
                                                       unsigned short* __restrict__ cbt) {
  __shared__ float lds[32 * 257];
  const int i0 = blockIdx.x * 16;    // 0..2032
  const int c0 = blockIdx.y * 32;
  const int t = threadIdx.x;
  const int io = t >> 4, f = t & 15;
  const int iclamp = min(i0 + io, F_TOT - 1);
  for (int cc = 0; cc < 32; ++cc)
    lds[cc * 257 + t] = coords[(size_t)(c0 + cc) * (F_TOT * CF) + iclamp * CF + f];
  __syncthreads();
  size_t obase = ((size_t)f * IPAD + (i0 + io)) * KDIM + c0;
#pragma unroll
  for (int cc = 0; cc < 32; cc += 4) {
    unsigned int lo = (unsigned int)f2bf(lds[(cc + 0) * 257 + t]) |
                      ((unsigned int)f2bf(lds[(cc + 1) * 257 + t]) << 16);
    unsigned int hi = (unsigned int)f2bf(lds[(cc + 2) * 257 + t]) |
                      ((unsigned int)f2bf(lds[(cc + 3) * 257 + t]) << 16);
    *(uint2*)(cbt + obase + cc) = make_uint2(lo, hi);
  }
}

// ------------------------------------------- k4: coords -> ct[f][i 2000][c] fp32
__global__ __launch_bounds__(256) void cvt_f32t_kernel(const float* __restrict__ coords,
                                                       float* __restrict__ ct) {
  __shared__ float lds[32 * 257];
  const int i0 = blockIdx.x * 16;    // 0..1984 (125 tiles exact)
  const int c0 = blockIdx.y * 32;
  const int t = threadIdx.x;
  const int io = t >> 4;
  for (int cc = 0; cc < 32; ++cc)
    lds[cc * 257 + t] = coords[(size_t)(c0 + cc) * (F_TOT * CF) + i0 * CF + t];
  __syncthreads();
  const int f = t & 15;
  size_t obase = ((size_t)f * F_TOT + (i0 + io)) * KDIM + c0;
#pragma unroll
  for (int cc = 0; cc < 32; cc += 4) {
    float4 v = make_float4(lds[(cc + 0) * 257 + t], lds[(cc + 1) * 257 + t],
                           lds[(cc + 2) * 257 + t], lds[(cc + 3) * 257 + t]);
    *(float4*)(ct + obase + cc) = v;
  }
}

// ------------------------------------------- k3: bf16 MFMA approx + top-10/chunk
// grid 512: f = bx&15, i-tile(128) = (bx>>4)&15, j-chunk(1000) = bx>>8.
// v10 staging: 32-col chunks, 2 x 24KB ping-pong buffers, depth-1 prefetch,
// vmcnt(6). LDS slot s (16B units) <- global (row=s>>2, seg=(s&3)^(row&3));
// fragment read applies the same XOR. Dl [128][64] f32 (32KB) aliases the
// buffers (js-top barrier fences Dl readers before restaging). 49KB LDS
// -> 3 blocks/CU.
__global__ __launch_bounds__(256, 3) void approx_kernel(const unsigned short* __restrict__ cbt,
                                                        const float* __restrict__ sq,
                                                        int* __restrict__ cand) {
  const int bx = blockIdx.x;
  const int f = bx & 15;
  const int it = (bx >> 4) & 15;
  const int jc = bx >> 8;
  const int ibase = it * 128;
  const int jcbase = jc * 1000;
  const int jlimit = jcbase + 1000;

  const int t = threadIdx.x;
  const int lane = t & 63;
  const int w = t >> 6;
  const int wi = w & 1, wj = w >> 1;
  const int lrow = lane & 15, lq = lane >> 4;

  // buf q at q*24576: A [0,8192) = [128 rows][32 cols] bf16 (64B rows),
  //                   B [8192,24576) = [256 rows][32 cols] bf16.
  // Dl [128][64] f32 (32KB) aliases buf0 + first 8KB of buf1.
  // sqj at 49152. Total 50176 B -> 3 blocks/CU.
  __shared__ char smem[50176];
  float* Dl = (float*)smem;
  float* sqj = (float*)(smem + 49152);

  const unsigned short* abase_g = cbt + ((size_t)f * IPAD + ibase) * KDIM;

  // scan identity: row ii, j-half (32 j per 64-j phase)
  const int ii = t & 127;
  const int half = t >> 7;
  const bool rowok = (ibase + ii < F_TOT);

  float bv[NCAND]; int bi[NCAND];
#pragma unroll
  for (int k = 0; k < NCAND; ++k) { bv[k] = __builtin_inff(); bi[k] = 0x7fffffff; }
  float sqi = rowok ? sq[(ibase + ii) * CF + f] : 0.0f;

  // A-fragment row geometry (per mi)
  int arow[4];
#pragma unroll
  for (int mi = 0; mi < 4; ++mi) arow[mi] = wi * 64 + mi * 16 + lrow;
  int brow[8];
#pragma unroll
  for (int nj = 0; nj < 8; ++nj) brow[nj] = wj * 128 + nj * 16 + lrow;

  for (int js = 0; js < 4; ++js) {
    const int jbase = jcbase + js * 256;
    __syncthreads();   // previous js's scan (Dl/sqj readers) done; staging may begin
    { int jg = jbase + t; sqj[t] = (jg < F_TOT) ? sq[jg * CF + f] : 0.0f; }

    f32x4 acc[4][8];
#pragma unroll
    for (int mi = 0; mi < 4; ++mi)
#pragma unroll
      for (int nj = 0; nj < 8; ++nj) acc[mi][nj] = (f32x4){0.f, 0.f, 0.f, 0.f};

    const unsigned short* bbase_g = cbt + ((size_t)f * IPAD + jbase) * KDIM;

    // stage one 32-col chunk (A: 2 instr, B: 4 instr) into buffer q.
    // source pre-swizzled: LDS slot s=(p*256+t) <- global (s>>2, (s&3)^((s>>2)&3))
#define STAGE32(q, c0)                                                                \
    {                                                                                 \
      char* Ad = smem + (q) * 24576;                                                  \
      char* Bd = Ad + 8192;                                                           \
      _Pragma("unroll")                                                               \
      for (int p = 0; p < 2; ++p) {                                                   \
        int s = p * 256 + t;                                                          \
        int r = s >> 2, sg = s & 3;                                                   \
        GLOAD_LDS16(abase_g + (size_t)r * KDIM + (c0) + ((sg ^ (r & 3)) << 3),        \
                    Ad + p * 4096 + (w << 10));                                       \
      }                                                                               \
      _Pragma("unroll")                                                               \
      for (int p = 0; p < 4; ++p) {                                                   \
        int s = p * 256 + t;                                                          \
        int r = s >> 2, sg = s & 3;                                                   \
        GLOAD_LDS16(bbase_g + (size_t)r * KDIM + (c0) + ((sg ^ (r & 3)) << 3),        \
                    Bd + p * 4096 + (w << 10));                                       \
      }                                                                               \
    }

    STAGE32(0, 0);                    // prologue: chunk 0 in flight

    for (int m = 0; m < 16; ++m) {
      const int cur = m & 1;
      const unsigned short* Al = (const unsigned short*)(smem + cur * 24576);
      const unsigned short* Bl = (const unsigned short*)(smem + cur * 24576 + 8192);
      // #1: all waves done reading the buffer about to be restaged
      __builtin_amdgcn_s_barrier();
      if (m < 15) {
        STAGE32((m + 1) & 1, (m + 1) * 32);
        // wait the OLDEST 6 (current buffer); 6 younger stay in flight
        asm volatile("s_waitcnt vmcnt(6)" ::: "memory");
      } else {
        asm volatile("s_waitcnt vmcnt(0)" ::: "memory");
      }
      // #2: every wave has waited its own loads -> buf[cur] fully populated
      __builtin_amdgcn_s_barrier();
      __builtin_amdgcn_sched_barrier(0);   // keep ds_reads below the fence
      bf16x8 a[4];
#pragma unroll
      for (int mi = 0; mi < 4; ++mi)
        a[mi] = *(const bf16x8*)(Al + arow[mi] * 32 + ((lq ^ (arow[mi] & 3)) << 3));
#pragma unroll
      for (int nj = 0; nj < 8; ++nj) {
        bf16x8 b = *(const bf16x8*)(Bl + brow[nj] * 32 + ((lq ^ (brow[nj] & 3)) << 3));
#pragma unroll
        for (int mi = 0; mi < 4; ++mi)
          acc[mi][nj] = __builtin_amdgcn_mfma_f32_16x16x32_bf16(a[mi], b, acc[mi][nj], 0, 0, 0);
      }
    }
#undef STAGE32

    // epilogue + scan: four phases of 64 j, all 256 threads scan.
    // Phase ph covers j in [ph*64, ph*64+64): produced by wave wj=ph>>1,
    // nj quads (ph&1)*4 .. +3. Top-10 lex-insert is arrival-order-independent
    // -> identical candidate set to the 2-phase version.
#pragma unroll
    for (int ph = 0; ph < 4; ++ph) {
      __syncthreads();
      if (wj == (ph >> 1)) {
#pragma unroll
        for (int mi = 0; mi < 4; ++mi) {
#pragma unroll
          for (int njq = 0; njq < 4; ++njq) {
            int nj = (ph & 1) * 4 + njq;
#pragma unroll
            for (int r = 0; r < 4; ++r) {
              int row = wi * 64 + mi * 16 + lq * 4 + r;   // C: col=lane&15, row=quad*4+reg
              int col = njq * 16 + lrow;                  // col within the 64-j quarter
              int q = col >> 2, rr = col & 3;
              Dl[row * 64 + (((q ^ (row & 7))) << 2) + rr] = acc[mi][nj][r];
            }
          }
        }
      }
      __syncthreads();
      if (rowok) {
        const int j0 = jbase + ph * 64 + half * 32;
        int cnt = jlimit - j0; if (cnt > 32) cnt = 32;
        for (int bb = 0; bb < 8; ++bb) {
          const int bo = bb * 4;
          if (bo >= cnt) break;
          const int qq = half * 8 + bb;
          const float4 g4 = *(const float4*)&Dl[ii * 64 + ((qq ^ (ii & 7)) << 2)];
          const float4 s4 = *(const float4*)&sqj[ph * 64 + half * 32 + bo];
          float d0 = fmaxf(fmaf(-2.0f, g4.x, sqi + s4.x), 0.0f);
          float d1 = fmaxf(fmaf(-2.0f, g4.y, sqi + s4.y), 0.0f);
          float d2 = fmaxf(fmaf(-2.0f, g4.z, sqi + s4.z), 0.0f);
          float d3 = fmaxf(fmaf(-2.0f, g4.w, sqi + s4.w), 0.0f);
          const int rem = cnt - bo;
          if (rem < 4) d3 = __builtin_inff();
          if (rem < 3) d2 = __builtin_inff();
          if (rem < 2) d1 = __builtin_inff();
          float mn = fminf(fminf(d0, d1), fminf(d2, d3));
          if (mn <= bv[NCAND - 1]) {           // gate; exact lex insert inside
            float dd[4] = {d0, d1, d2, d3};
#pragma unroll
            for (int e = 0; e < 4; ++e) {      // ascending j within the quad
              float d = dd[e]; int jg = j0 + bo + e;
              if (d < bv[NCAND - 1] || (d == bv[NCAND - 1] && jg < bi[NCAND - 1])) {
                float cv = d; int ci = jg;
#pragma unroll
                for (int k = 0; k < NCAND; ++k) {
                  bool lt = (cv < bv[k]) || (cv == bv[k] && ci < bi[k]);
                  float tv = lt ? bv[k] : cv; int ti = lt ? bi[k] : ci;
                  bv[k] = lt ? cv : bv[k];    bi[k] = lt ? ci : bi[k];
                  cv = tv; ci = ti;
                }
              }
            }
          }
        }
      }
    }
  }

  // merge the two j-half partial top-10s (lex-exact == chunk top-10)
  __syncthreads();
  if (half == 1 && rowok) {
    float* wrow = &Dl[ii * 64];
#pragma unroll
    for (int k = 0; k < NCAND; ++k) { wrow[k] = bv[k]; *(int*)&wrow[NCAND + k] = bi[k]; }
  }
  __syncthreads();
  if (half == 0 && rowok) {
    const float* wrow = &Dl[ii * 64];
    float ov[NCAND]; int oi[NCAND];
#pragma unroll
    for (int k = 0; k < NCAND; ++k) { ov[k] = wrow[k]; oi[k] = *(const int*)&wrow[NCAND + k]; }
    float mv[NCAND]; int mj[NCAND];
    int p = 0, q = 0;
#pragma unroll
    for (int k = 0; k < NCAND; ++k) {          // two-pointer lex merge, pick 10 smallest
      bool mine = (q >= NCAND) || ((p < NCAND) &&
                  ((bv[p] < ov[q]) || (bv[p] == ov[q] && bi[p] < oi[q])));
      mv[k] = mine ? bv[p] : ov[q];
      mj[k] = mine ? bi[p] : oi[q];
      p += mine ? 1 : 0; q += mine ? 0 : 1;
    }
    (void)mv;
    // sort the 10 candidate j's ascending (odd-even transposition)
#pragma unroll
    for (int r = 0; r < NCAND; ++r) {
#pragma unroll
      for (int k = 0; k + 1 < NCAND; ++k) {
        if (((k ^ r) & 1) == 0) {
          int lo = min(mj[k], mj[k + 1]);
          int hi = max(mj[k], mj[k + 1]);
          mj[k] = lo; mj[k + 1] = hi;
        }
      }
    }
    int* dst = cand + ((size_t)(ibase + ii) * CF + f) * NCTOT + jc * NCAND;
#pragma unroll
    for (int k = 0; k < NCAND; ++k) dst[k] = mj[k];
  }
}

// ------------------------------------------- k5: exact distances, wave-cooperative
// v9 (validated): 8 lanes per candidate-pair, fully-used 128B lines,
// shfl_xor butterfly reduce, lane 0 stores.
__global__ __launch_bounds__(256) void refine_dist_kernel(const float* __restrict__ ct,
                                                          const float* __restrict__ sq,
                                                          const int* __restrict__ cand,
                                                          float* __restrict__ dval) {
  const int NWG = (F_TOT * CF * (NCTOT / 2)) / 32;   // 10000, %8 == 0
  int orig = blockIdx.x;
  int bid = (orig & 7) * (NWG / 8) + (orig >> 3);    // bijective XCD chunking
  int u = bid * 32 + (threadIdx.x >> 3);             // unit 0..319999
  const int k = threadIdx.x & 7;
  // f-major: u = f*(2000*10) + i*10 + m
  int f = u / (F_TOT * (NCTOT / 2));
  int y = u - f * (F_TOT * (NCTOT / 2));
  int i = y / (NCTOT / 2);
  int m = y - i * (NCTOT / 2);
  int pf = i * CF + f;
  int j0 = cand[(size_t)pf * NCTOT + 2 * m];
  int j1 = cand[(size_t)pf * NCTOT + 2 * m + 1];
  const float* a = ct + ((size_t)f * F_TOT + i) * KDIM + k * 4;
  const float* p = ct + ((size_t)f * F_TOT + j0) * KDIM + k * 4;
  const float* q = ct + ((size_t)f * F_TOT + j1) * KDIM + k * 4;
  float g0 = 0.0f, g1 = 0.0f;
#pragma unroll
  for (int n = 0; n < 16; ++n) {
    float4 av = *(const float4*)(a + n * 32);
    float4 pv = *(const float4*)(p + n * 32);
    float4 qv = *(const float4*)(q + n * 32);
    g0 = fmaf(av.x, pv.x, g0); g1 = fmaf(av.x, qv.x, g1);
    g0 = fmaf(av.y, pv.y, g0); g1 = fmaf(av.y, qv.y, g1);
    g0 = fmaf(av.z, pv.z, g0); g1 = fmaf(av.z, qv.z, g1);
    g0 = fmaf(av.w, pv.w, g0); g1 = fmaf(av.w, qv.w, g1);
  }
#pragma unroll
  for (int off = 1; off < 8; off <<= 1) {
    g0 += __shfl_xor(g0, off);
    g1 += __shfl_xor(g1, off);
  }
  if (k == 0) {
    float sqi = sq[i * CF + f];
    float d0 = fmaf(-2.0f, g0, sqi + sq[j0 * CF + f]); d0 = fmaxf(d0, 0.0f);
    float d1 = fmaf(-2.0f, g1, sqi + sq[j1 * CF + f]); d1 = fmaxf(d1, 0.0f);
    dval[(size_t)pf * NCTOT + 2 * m]     = d0;
    dval[(size_t)pf * NCTOT + 2 * m + 1] = d1;
  }
}

// ------------------------------------------- k6: top-8 select (ascending-j, strict <)
__global__ __launch_bounds__(256) void select_kernel(const float* __restrict__ dval,
                                                     const int* __restrict__ cand,
                                                     int* __restrict__ fidx) {
  int pf = blockIdx.x * 256 + threadIdx.x;   // (i*16+f), 0..31999
  if (pf >= F_TOT * CF) return;
  int i = pf >> 4, f = pf & 15;
  float bval[NB_K]; int bidx[NB_K];
#pragma unroll
  for (int k = 0; k < NB_K; ++k) { bval[k] = __builtin_inff(); bidx[k] = 0; }
#pragma unroll
  for (int m = 0; m < NCTOT; ++m) {          // ascending j (chunks disjoint ascending)
    float d = dval[(size_t)pf * NCTOT + m];
    int j = cand[(size_t)pf * NCTOT + m];
    if (d < bval[NB_K - 1]) {
      float cv = d; int ci = j;
#pragma unroll
      for (int k = 0; k < NB_K; ++k)
        if (cv < bval[k]) {
          float tv = bval[k]; bval[k] = cv; cv = tv;
          int ti = bidx[k]; bidx[k] = ci; ci = ti;
        }
    }
  }
#pragma unroll
  for (int k = 0; k < NB_K; ++k)
    fidx[((size_t)i * NB_K + k) * CF + f] = bidx[k];
}

// ---------------------------------------------------------------- k7: gather
__global__ __launch_bounds__(256) void gather_kernel(const float* __restrict__ inputs,
                                                     const int* __restrict__ fidx,
                                                     float* __restrict__ out) {
  int b = blockIdx.y;
  int x = blockIdx.x * 256 + threadIdx.x;    // m*16+c
  int c = x & 15;
  int n = fidx[x];
  out[(size_t)b * (F_TOT * NB_K * CF) + x] =
      inputs[(size_t)b * (F_TOT * CF) + n * CF + c];
}

// ---------------------------------------------------------------- launcher
extern "C" void kernel_launch(void* const* d_in, const int* in_sizes, int n_in,
                              void* d_out, int out_size, void* d_ws, size_t ws_size,
                              hipStream_t stream) {
  const float* inputs = (const float*)d_in[0];   // (64, 2000, 16)
  const float* coords = (const float*)d_in[1];   // (512, 2000, 16)
  float* out = (float*)d_out;

  unsigned short* cbt = (unsigned short*)d_out;  // 16*2048*512 bf16 (phase 1)
  float* ct = (float*)d_out;                     // 16*2000*512 f32 (phase 2, == out_size)

  float* sq = (float*)d_ws;                      // 32768 floats
  int* cand = (int*)d_ws + 32768;                // 32000*20 ints
  float* dval = (float*)d_ws + 32768 + 32000 * NCTOT; // 32000*20 floats
  int* fidx = (int*)d_ws + 32768 + 2 * 32000 * NCTOT; // 256000 ints

  sq_kernel<<<F_TOT, 256, 0, stream>>>(coords, sq);
  cvt_bf16_kernel<<<dim3(IPAD / 16, KDIM / 32), 256, 0, stream>>>(coords, cbt);
  approx_kernel<<<512, 256, 0, stream>>>(cbt, sq, cand);
  cvt_f32t_kernel<<<dim3(F_TOT / 16, KDIM / 32), 256, 0, stream>>>(coords, ct);
  refine_dist_kernel<<<(F_TOT * CF * (NCTOT / 2)) / 32, 256, 0, stream>>>(ct, sq, cand, dval);
  select_kernel<<<(F_TOT * CF + 255) / 256, 256, 0, stream>>>(dval, cand, fidx);
  dim3 g7((F_TOT * NB_K * CF) / 256, 64);
  gather_kernel<<<g7, 256, 0, stream>>>(inputs, fidx, out);
}

// Round 6
// 802.437 us; speedup vs baseline: 1.0968x; 1.0968x over previous
//
#include <hip/hip_runtime.h>
#include <math.h>

// PhyloNeighbours: per-filter (16) kNN (k=8) over 2000 features, 512-dim coords.
// v11: (a) approx at a TRUE 3 blocks/CU; (b) refine+select fused.
// v10 post-mortem: launch_bounds(256,3) capped VGPR at 84 -> 128-VGPR acc
// spilled to scratch (WRITE_SIZE 68->271MB) AND grid 512 made 3/CU
// unreachable anyway. v10's 50KB layout + 4-phase scan PASSED -> validated.
// v11 approx: v10 layout + launch_bounds(256,2) (natural VGPR ~128; runtime
// occupancy from actual LDS 50KB = 3 blocks/CU) + grid 768 via NCH=3 chunks
// of 672 j (16f x 16it x 3jc = exactly 3/CU, one clean round). NCAND stays 10
// (approx-rank safety margin preserved). IPAD 2048->2112 covers the deepest
// staged B row (2111). refine+select fused: one 256-thr block = 2 pf x 16
// units (unit 15 idle); v9's validated 8-lane dot + shfl butterfly -> LDS;
// threads 0-1 run the validated ascending-j strict-< top-8 over 30 cands and
// write fidx. dval eliminated -> ws = sq + cand(30/pf) + fidx = 5.0MB.
//
// Memory plan:
//   d_out: phase 1 holds cbt[f][2112][512] bf16 (33 MB); phase 2 holds
//          ct[f][2000][512] fp32 (exactly out_size floats); final gather output.
//   d_ws : sq 128KB + cand 3.84MB + fidx 1MB ~= 5.0 MB.

#define F_TOT 2000
#define CF    16
#define KDIM  512
#define NB_K  8
#define IPAD  2112
#define NCAND 10
#define NCH   3
#define CHUNK 672
#define JS_N  3
#define NCTOT (NCAND * NCH)

typedef __attribute__((ext_vector_type(8))) short bf16x8;
typedef __attribute__((ext_vector_type(4))) float f32x4;

__device__ inline unsigned short f2bf(float x) {
  unsigned int u = __float_as_uint(x);
  return (unsigned short)((u + 0x7fffu + ((u >> 16) & 1u)) >> 16);
}

// async 16B global -> LDS (LDS dest: wave-uniform base + lane*16)
#define GLOAD_LDS16(gp, lp)                                                          \
  __builtin_amdgcn_global_load_lds((const __attribute__((address_space(1))) void*)(gp), \
                                   (__attribute__((address_space(3))) void*)(lp), 16, 0, 0)

// ---------------------------------------------------------------- k1: sq (fp64)
// VALIDATED rounds 1-4 — do not change arithmetic.
__global__ __launch_bounds__(256) void sq_kernel(const float* __restrict__ coords,
                                                 float* __restrict__ sq_out) {
  int i = blockIdx.x;
  int t = threadIdx.x;
  int f = t & 15;
  int cg = t >> 4;
  const float* base = coords + (size_t)i * CF + f;
  double s = 0.0;
  for (int c = cg * 32; c < cg * 32 + 32; ++c) {
    float v = base[(size_t)c * (F_TOT * CF)];
    s += (double)v * (double)v;
  }
  __shared__ double red[256];
  red[t] = s;
  __syncthreads();
  if (cg == 0) {
    double tot = 0.0;
#pragma unroll
    for (int g = 0; g < 16; ++g) tot += red[g * 16 + f];
    sq_out[i * CF + f] = (float)tot;
  }
}

// ------------------------------------------- k2: coords -> cbt[f][i pad2112][c] bf16
__global__ __launch_bounds__(256) void cvt_bf16_kernel(const float* __restrict__ coords,
                                                       unsigned short* __restrict__ cbt) {
  __shared__ float lds[32 * 257];
  const int i0 = blockIdx.x * 16;    // 0..2096
  const int c0 = blockIdx.y * 32;
  const int t = threadIdx.x;
  const int io = t >> 4, f = t & 15;
  const int iclamp = min(i0 + io, F_TOT - 1);
  for (int cc = 0; cc < 32; ++cc)
    lds[cc * 257 + t] = coords[(size_t)(c0 + cc) * (F_TOT * CF) + iclamp * CF + f];
  __syncthreads();
  size_t obase = ((size_t)f * IPAD + (i0 + io)) * KDIM + c0;
#pragma unroll
  for (int cc = 0; cc < 32; cc += 4) {
    unsigned int lo = (unsigned int)f2bf(lds[(cc + 0) * 257 + t]) |
                      ((unsigned int)f2bf(lds[(cc + 1) * 257 + t]) << 16);
    unsigned int hi = (unsigned int)f2bf(lds[(cc + 2) * 257 + t]) |
                      ((unsigned int)f2bf(lds[(cc + 3) * 257 + t]) << 16);
    *(uint2*)(cbt + obase + cc) = make_uint2(lo, hi);
  }
}

// ------------------------------------------- k4: coords -> ct[f][i 2000][c] fp32
__global__ __launch_bounds__(256) void cvt_f32t_kernel(const float* __restrict__ coords,
                                                       float* __restrict__ ct) {
  __shared__ float lds[32 * 257];
  const int i0 = blockIdx.x * 16;    // 0..1984 (125 tiles exact)
  const int c0 = blockIdx.y * 32;
  const int t = threadIdx.x;
  const int io = t >> 4;
  for (int cc = 0; cc < 32; ++cc)
    lds[cc * 257 + t] = coords[(size_t)(c0 + cc) * (F_TOT * CF) + i0 * CF + t];
  __syncthreads();
  const int f = t & 15;
  size_t obase = ((size_t)f * F_TOT + (i0 + io)) * KDIM + c0;
#pragma unroll
  for (int cc = 0; cc < 32; cc += 4) {
    float4 v = make_float4(lds[(cc + 0) * 257 + t], lds[(cc + 1) * 257 + t],
                           lds[(cc + 2) * 257 + t], lds[(cc + 3) * 257 + t]);
    *(float4*)(ct + obase + cc) = v;
  }
}

// ------------------------------------------- k3: bf16 MFMA approx + top-10/chunk
// grid 768: f = bx&15, i-tile(128) = (bx>>4)&15, j-chunk(672) = bx>>8.
// v10-validated staging: 32-col chunks, 2 x 24KB ping-pong buffers, depth-1
// prefetch, vmcnt(6). LDS slot s (16B units) <- global (row=s>>2,
// seg=(s&3)^(row&3)); fragment read applies the same XOR. Dl [128][64] f32
// (32KB) aliases the buffers. 49KB LDS + natural VGPR (~128) -> 3 blocks/CU.
__global__ __launch_bounds__(256, 2) void approx_kernel(const unsigned short* __restrict__ cbt,
                                                        const float* __restrict__ sq,
                                                        int* __restrict__ cand) {
  const int bx = blockIdx.x;
  const int f = bx & 15;
  const int it = (bx >> 4) & 15;
  const int jc = bx >> 8;            // 0..2
  const int ibase = it * 128;
  const int jcbase = jc * CHUNK;
  int jlimit = jcbase + CHUNK;
  if (jlimit > F_TOT) jlimit = F_TOT;

  const int t = threadIdx.x;
  const int lane = t & 63;
  const int w = t >> 6;
  const int wi = w & 1, wj = w >> 1;
  const int lrow = lane & 15, lq = lane >> 4;

  // buf q at q*24576: A [0,8192) = [128 rows][32 cols] bf16 (64B rows),
  //                   B [8192,24576) = [256 rows][32 cols] bf16.
  // Dl [128][64] f32 (32KB) aliases buf0 + first 8KB of buf1.
  // sqj at 49152. Total 50176 B -> 3 blocks/CU.
  __shared__ char smem[50176];
  float* Dl = (float*)smem;
  float* sqj = (float*)(smem + 49152);

  const unsigned short* abase_g = cbt + ((size_t)f * IPAD + ibase) * KDIM;

  // scan identity: row ii, j-half (32 j per 64-j phase)
  const int ii = t & 127;
  const int half = t >> 7;
  const bool rowok = (ibase + ii < F_TOT);

  float bv[NCAND]; int bi[NCAND];
#pragma unroll
  for (int k = 0; k < NCAND; ++k) { bv[k] = __builtin_inff(); bi[k] = 0x7fffffff; }
  float sqi = rowok ? sq[(ibase + ii) * CF + f] : 0.0f;

  // A-fragment row geometry (per mi)
  int arow[4];
#pragma unroll
  for (int mi = 0; mi < 4; ++mi) arow[mi] = wi * 64 + mi * 16 + lrow;
  int brow[8];
#pragma unroll
  for (int nj = 0; nj < 8; ++nj) brow[nj] = wj * 128 + nj * 16 + lrow;

  for (int js = 0; js < JS_N; ++js) {
    const int jbase = jcbase + js * 256;
    __syncthreads();   // previous js's scan (Dl/sqj readers) done; staging may begin
    { int jg = jbase + t; sqj[t] = (jg < F_TOT) ? sq[jg * CF + f] : 0.0f; }

    f32x4 acc[4][8];
#pragma unroll
    for (int mi = 0; mi < 4; ++mi)
#pragma unroll
      for (int nj = 0; nj < 8; ++nj) acc[mi][nj] = (f32x4){0.f, 0.f, 0.f, 0.f};

    const unsigned short* bbase_g = cbt + ((size_t)f * IPAD + jbase) * KDIM;

    // stage one 32-col chunk (A: 2 instr, B: 4 instr per wave) into buffer q.
    // source pre-swizzled: LDS slot s=(p*256+t) <- global (s>>2, (s&3)^((s>>2)&3))
#define STAGE32(q, c0)                                                                \
    {                                                                                 \
      char* Ad = smem + (q) * 24576;                                                  \
      char* Bd = Ad + 8192;                                                           \
      _Pragma("unroll")                                                               \
      for (int p = 0; p < 2; ++p) {                                                   \
        int s = p * 256 + t;                                                          \
        int r = s >> 2, sg = s & 3;                                                   \
        GLOAD_LDS16(abase_g + (size_t)r * KDIM + (c0) + ((sg ^ (r & 3)) << 3),        \
                    Ad + p * 4096 + (w << 10));                                       \
      }                                                                               \
      _Pragma("unroll")                                                               \
      for (int p = 0; p < 4; ++p) {                                                   \
        int s = p * 256 + t;                                                          \
        int r = s >> 2, sg = s & 3;                                                   \
        GLOAD_LDS16(bbase_g + (size_t)r * KDIM + (c0) + ((sg ^ (r & 3)) << 3),        \
                    Bd + p * 4096 + (w << 10));                                       \
      }                                                                               \
    }

    STAGE32(0, 0);                    // prologue: chunk 0 in flight

    for (int m = 0; m < 16; ++m) {
      const int cur = m & 1;
      const unsigned short* Al = (const unsigned short*)(smem + cur * 24576);
      const unsigned short* Bl = (const unsigned short*)(smem + cur * 24576 + 8192);
      // #1: all waves done reading the buffer about to be restaged
      __builtin_amdgcn_s_barrier();
      if (m < 15) {
        STAGE32((m + 1) & 1, (m + 1) * 32);
        // wait the OLDEST outstanding down to 6 (current buffer landed);
        // the 6 just-issued stay in flight
        asm volatile("s_waitcnt vmcnt(6)" ::: "memory");
      } else {
        asm volatile("s_waitcnt vmcnt(0)" ::: "memory");
      }
      // #2: every wave has waited its own loads -> buf[cur] fully populated
      __builtin_amdgcn_s_barrier();
      __builtin_amdgcn_sched_barrier(0);   // keep ds_reads below the fence
      bf16x8 a[4];
#pragma unroll
      for (int mi = 0; mi < 4; ++mi)
        a[mi] = *(const bf16x8*)(Al + arow[mi] * 32 + ((lq ^ (arow[mi] & 3)) << 3));
#pragma unroll
      for (int nj = 0; nj < 8; ++nj) {
        bf16x8 b = *(const bf16x8*)(Bl + brow[nj] * 32 + ((lq ^ (brow[nj] & 3)) << 3));
#pragma unroll
        for (int mi = 0; mi < 4; ++mi)
          acc[mi][nj] = __builtin_amdgcn_mfma_f32_16x16x32_bf16(a[mi], b, acc[mi][nj], 0, 0, 0);
      }
    }
#undef STAGE32

    // epilogue + scan: four phases of 64 j, all 256 threads scan.
    // Phase ph covers j in [ph*64, ph*64+64): produced by wave wj=ph>>1,
    // nj quads (ph&1)*4 .. +3. Top-10 lex-insert is arrival-order-independent.
#pragma unroll
    for (int ph = 0; ph < 4; ++ph) {
      __syncthreads();
      if (wj == (ph >> 1)) {
#pragma unroll
        for (int mi = 0; mi < 4; ++mi) {
#pragma unroll
          for (int njq = 0; njq < 4; ++njq) {
            int nj = (ph & 1) * 4 + njq;
#pragma unroll
            for (int r = 0; r < 4; ++r) {
              int row = wi * 64 + mi * 16 + lq * 4 + r;   // C: col=lane&15, row=quad*4+reg
              int col = njq * 16 + lrow;                  // col within the 64-j quarter
              int q = col >> 2, rr = col & 3;
              Dl[row * 64 + (((q ^ (row & 7))) << 2) + rr] = acc[mi][nj][r];
            }
          }
        }
      }
      __syncthreads();
      if (rowok) {
        const int j0 = jbase + ph * 64 + half * 32;
        int cnt = jlimit - j0; if (cnt > 32) cnt = 32;
        for (int bb = 0; bb < 8; ++bb) {
          const int bo = bb * 4;
          if (bo >= cnt) break;
          const int qq = half * 8 + bb;
          const float4 g4 = *(const float4*)&Dl[ii * 64 + ((qq ^ (ii & 7)) << 2)];
          const float4 s4 = *(const float4*)&sqj[ph * 64 + half * 32 + bo];
          float d0 = fmaxf(fmaf(-2.0f, g4.x, sqi + s4.x), 0.0f);
          float d1 = fmaxf(fmaf(-2.0f, g4.y, sqi + s4.y), 0.0f);
          float d2 = fmaxf(fmaf(-2.0f, g4.z, sqi + s4.z), 0.0f);
          float d3 = fmaxf(fmaf(-2.0f, g4.w, sqi + s4.w), 0.0f);
          const int rem = cnt - bo;
          if (rem < 4) d3 = __builtin_inff();
          if (rem < 3) d2 = __builtin_inff();
          if (rem < 2) d1 = __builtin_inff();
          float mn = fminf(fminf(d0, d1), fminf(d2, d3));
          if (mn <= bv[NCAND - 1]) {           // gate; exact lex insert inside
            float dd[4] = {d0, d1, d2, d3};
#pragma unroll
            for (int e = 0; e < 4; ++e) {      // ascending j within the quad
              float d = dd[e]; int jg = j0 + bo + e;
              if (d < bv[NCAND - 1] || (d == bv[NCAND - 1] && jg < bi[NCAND - 1])) {
                float cv = d; int ci = jg;
#pragma unroll
                for (int k = 0; k < NCAND; ++k) {
                  bool lt = (cv < bv[k]) || (cv == bv[k] && ci < bi[k]);
                  float tv = lt ? bv[k] : cv; int ti = lt ? bi[k] : ci;
                  bv[k] = lt ? cv : bv[k];    bi[k] = lt ? ci : bi[k];
                  cv = tv; ci = ti;
                }
              }
            }
          }
        }
      }
    }
  }

  // merge the two j-half partial top-10s (lex-exact == chunk top-10)
  __syncthreads();
  if (half == 1 && rowok) {
    float* wrow = &Dl[ii * 64];
#pragma unroll
    for (int k = 0; k < NCAND; ++k) { wrow[k] = bv[k]; *(int*)&wrow[NCAND + k] = bi[k]; }
  }
  __syncthreads();
  if (half == 0 && rowok) {
    const float* wrow = &Dl[ii * 64];
    float ov[NCAND]; int oi[NCAND];
#pragma unroll
    for (int k = 0; k < NCAND; ++k) { ov[k] = wrow[k]; oi[k] = *(const int*)&wrow[NCAND + k]; }
    float mv[NCAND]; int mj[NCAND];
    int p = 0, q = 0;
#pragma unroll
    for (int k = 0; k < NCAND; ++k) {          // two-pointer lex merge, pick 10 smallest
      bool mine = (q >= NCAND) || ((p < NCAND) &&
                  ((bv[p] < ov[q]) || (bv[p] == ov[q] && bi[p] < oi[q])));
      mv[k] = mine ? bv[p] : ov[q];
      mj[k] = mine ? bi[p] : oi[q];
      p += mine ? 1 : 0; q += mine ? 0 : 1;
    }
    (void)mv;
    // sort the 10 candidate j's ascending (odd-even transposition)
#pragma unroll
    for (int r = 0; r < NCAND; ++r) {
#pragma unroll
      for (int k = 0; k + 1 < NCAND; ++k) {
        if (((k ^ r) & 1) == 0) {
          int lo = min(mj[k], mj[k + 1]);
          int hi = max(mj[k], mj[k + 1]);
          mj[k] = lo; mj[k + 1] = hi;
        }
      }
    }
    int* dst = cand + ((size_t)(ibase + ii) * CF + f) * NCTOT + jc * NCAND;
#pragma unroll
    for (int k = 0; k < NCAND; ++k) dst[k] = mj[k];
  }
}

// ------------------------------------------- k5: exact distances + top-8, FUSED
// v9's validated wave-cooperative distances (8 lanes/pair, fully-used 128B
// lines, shfl_xor butterfly) feed LDS; threads 0-1 run the validated
// ascending-j strict-< top-8 over the 30 candidates and write fidx directly.
// Block = 2 pf x 16 units (unit 15 idle; 15 real pairs = 30 cands).
__global__ __launch_bounds__(256) void refine_select_kernel(const float* __restrict__ ct,
                                                            const float* __restrict__ sq,
                                                            const int* __restrict__ cand,
                                                            int* __restrict__ fidx) {
  const int NWG = (F_TOT * CF) / 2;              // 16000, %8 == 0
  int orig = blockIdx.x;
  int bid = (orig & 7) * (NWG / 8) + (orig >> 3);  // bijective XCD chunking
  const int t = threadIdx.x;
  const int u = t >> 3;                          // 0..31
  const int k = t & 7;
  const int pl = u >> 4;                         // pf slot in block: 0..1
  const int mu = u & 15;                         // pair 0..14; 15 = idle
  __shared__ float lds_d[2 * NCTOT];

  // f-major pf id: P = f*2000 + i  (consecutive bids -> same f, consecutive i)
  int P = bid * 2 + pl;
  int f = P / F_TOT;
  int i = P - f * F_TOT;
  int pf = i * CF + f;

  if (mu < NCTOT / 2) {
    int j0 = cand[(size_t)pf * NCTOT + 2 * mu];
    int j1 = cand[(size_t)pf * NCTOT + 2 * mu + 1];
    const float* a = ct + ((size_t)f * F_TOT + i) * KDIM + k * 4;
    const float* p = ct + ((size_t)f * F_TOT + j0) * KDIM + k * 4;
    const float* q = ct + ((size_t)f * F_TOT + j1) * KDIM + k * 4;
    float g0 = 0.0f, g1 = 0.0f;
#pragma unroll
    for (int n = 0; n < 16; ++n) {
      float4 av = *(const float4*)(a + n * 32);
      float4 pv = *(const float4*)(p + n * 32);
      float4 qv = *(const float4*)(q + n * 32);
      g0 = fmaf(av.x, pv.x, g0); g1 = fmaf(av.x, qv.x, g1);
      g0 = fmaf(av.y, pv.y, g0); g1 = fmaf(av.y, qv.y, g1);
      g0 = fmaf(av.z, pv.z, g0); g1 = fmaf(av.z, qv.z, g1);
      g0 = fmaf(av.w, pv.w, g0); g1 = fmaf(av.w, qv.w, g1);
    }
#pragma unroll
    for (int off = 1; off < 8; off <<= 1) {
      g0 += __shfl_xor(g0, off);
      g1 += __shfl_xor(g1, off);
    }
    if (k == 0) {
      float sqi = sq[i * CF + f];
      float d0 = fmaf(-2.0f, g0, sqi + sq[j0 * CF + f]); d0 = fmaxf(d0, 0.0f);
      float d1 = fmaf(-2.0f, g1, sqi + sq[j1 * CF + f]); d1 = fmaxf(d1, 0.0f);
      lds_d[pl * NCTOT + 2 * mu]     = d0;
      lds_d[pl * NCTOT + 2 * mu + 1] = d1;
    }
  }
  __syncthreads();
  if (t < 2) {
    int P2 = bid * 2 + t;
    int f2 = P2 / F_TOT;
    int i2 = P2 - f2 * F_TOT;
    int pf2 = i2 * CF + f2;
    float bval[NB_K]; int bidx[NB_K];
#pragma unroll
    for (int kk = 0; kk < NB_K; ++kk) { bval[kk] = __builtin_inff(); bidx[kk] = 0; }
    for (int mm = 0; mm < NCTOT; ++mm) {       // ascending j (chunks disjoint ascending)
      float d = lds_d[t * NCTOT + mm];
      int j = cand[(size_t)pf2 * NCTOT + mm];
      if (d < bval[NB_K - 1]) {
        float cv = d; int ci = j;
#pragma unroll
        for (int kk = 0; kk < NB_K; ++kk)
          if (cv < bval[kk]) {
            float tv = bval[kk]; bval[kk] = cv; cv = tv;
            int ti = bidx[kk]; bidx[kk] = ci; ci = ti;
          }
      }
    }
#pragma unroll
    for (int kk = 0; kk < NB_K; ++kk)
      fidx[((size_t)i2 * NB_K + kk) * CF + f2] = bidx[kk];
  }
}

// ---------------------------------------------------------------- k7: gather
__global__ __launch_bounds__(256) void gather_kernel(const float* __restrict__ inputs,
                                                     const int* __restrict__ fidx,
                                                     float* __restrict__ out) {
  int b = blockIdx.y;
  int x = blockIdx.x * 256 + threadIdx.x;    // m*16+c
  int c = x & 15;
  int n = fidx[x];
  out[(size_t)b * (F_TOT * NB_K * CF) + x] =
      inputs[(size_t)b * (F_TOT * CF) + n * CF + c];
}

// ---------------------------------------------------------------- launcher
extern "C" void kernel_launch(void* const* d_in, const int* in_sizes, int n_in,
                              void* d_out, int out_size, void* d_ws, size_t ws_size,
                              hipStream_t stream) {
  const float* inputs = (const float*)d_in[0];   // (64, 2000, 16)
  const float* coords = (const float*)d_in[1];   // (512, 2000, 16)
  float* out = (float*)d_out;

  unsigned short* cbt = (unsigned short*)d_out;  // 16*2112*512 bf16 (phase 1, 33MB)
  float* ct = (float*)d_out;                     // 16*2000*512 f32 (phase 2, == out_size)

  float* sq = (float*)d_ws;                      // 32768 floats
  int* cand = (int*)d_ws + 32768;                // 32000*30 ints
  int* fidx = (int*)d_ws + 32768 + 32000 * NCTOT; // 256000 ints

  sq_kernel<<<F_TOT, 256, 0, stream>>>(coords, sq);
  cvt_bf16_kernel<<<dim3(IPAD / 16, KDIM / 32), 256, 0, stream>>>(coords, cbt);
  approx_kernel<<<16 * 16 * NCH, 256, 0, stream>>>(cbt, sq, cand);
  cvt_f32t_kernel<<<dim3(F_TOT / 16, KDIM / 32), 256, 0, stream>>>(coords, ct);
  refine_select_kernel<<<(F_TOT * CF) / 2, 256, 0, stream>>>(ct, sq, cand, fidx);
  dim3 g7((F_TOT * NB_K * CF) / 256, 64);
  gather_kernel<<<g7, 256, 0, stream>>>(inputs, fidx, out);
}